// Round 4
// baseline (285.493 us; speedup 1.0000x reference)
//
#include <hip/hip_runtime.h>

// BoxFilter: 21x21 all-ones box, circular pad, x: f32[8,1,2048,2048].
// v4c: occupancy-first. Tile 128x32, LDS 19.97 KB -> 8 blocks/CU (32 waves).
// Phase 1: float4 column loads + 21-tap vertical running sums -> LDS (b128).
// Phase 2: b128 window reads, horizontal sliding sums, non-temporal stores
// via native ext_vector_type (HIP float4 class is rejected by the builtin).

#define HH 2048
#define WW 2048
#define RAD 10
#define DIAM 21
#define TH 32
#define TW 128
#define NC4 38          // float4 colsum slots: image cols [w0-12, w0+139]
#define SSTR 156        // LDS row stride (dwords)

typedef float nfloat4 __attribute__((ext_vector_type(4)));

__global__ __launch_bounds__(256) void box_filter_v4(
    const float* __restrict__ x, float* __restrict__ out) {
  __shared__ float sCS[TH * SSTR];  // 19968 B: colsum[r][a], a = image col - (w0-12)

  const int n = blockIdx.z;
  const int h0 = blockIdx.y * TH;
  const int w0 = blockIdx.x * TW;
  const float* __restrict__ xp = x + (size_t)n * (HH * WW);
  float* __restrict__ op = out + (size_t)n * (HH * WW);
  const int tid = threadIdx.x;

  // ---- Phase 1: vertical sliding sums, float4-vectorized columns.
  // 38 col-quads x 2 row-groups = 76 tasks. Each: 36 float4 row loads
  // (coalesced), 21-tap running sum slid over 16 output rows, b128 LDS writes.
  if (tid < NC4 * 2) {
    const int c4 = tid % NC4;            // 0..37
    const int g = tid / NC4;             // row-group 0..1
    const int gc = (w0 - 12 + 4 * c4) & (WW - 1);  // circular in W, 16B aligned
    const int rbase = h0 + 16 * g - RAD;
    nfloat4 v[36];
#pragma unroll
    for (int k = 0; k < 36; ++k)
      v[k] = *(const nfloat4*)(xp + (size_t)((rbase + k) & (HH - 1)) * WW + gc);
    nfloat4 s = v[0];
#pragma unroll
    for (int k = 1; k < DIAM; ++k) s += v[k];
    *(nfloat4*)&sCS[(16 * g) * SSTR + 4 * c4] = s;
#pragma unroll
    for (int i = 1; i < 16; ++i) {
      s += v[i + 20] - v[i - 1];
      *(nfloat4*)&sCS[(16 * g + i) * SSTR + 4 * c4] = s;
    }
  }
  __syncthreads();

  // ---- Phase 2: horizontal sliding sums. thread -> (row r, one 16-col chunk).
  // 32 rows x 8 chunks = 256 tasks. Window of 40 colsums as 10 aligned b128;
  // output col j (in chunk) sums window[j+2 .. j+22].
  {
    const int r = tid >> 3;              // 0..31
    const int cg = tid & 7;              // 0..7
    const float* row = &sCS[r * SSTR + 16 * cg];
    float* orow = &op[(size_t)(h0 + r) * WW + w0 + 16 * cg];
    __align__(16) float w[40];
#pragma unroll
    for (int k = 0; k < 10; ++k)
      *(nfloat4*)&w[4 * k] = *(const nfloat4*)&row[4 * k];
    float s = w[2];
#pragma unroll
    for (int k = 3; k <= 22; ++k) s += w[k];
    float o[16];
    o[0] = s;
#pragma unroll
    for (int j = 1; j < 16; ++j) {
      s += w[j + 22] - w[j + 1];
      o[j] = s;
    }
#pragma unroll
    for (int q = 0; q < 4; ++q) {
      nfloat4 ov = {o[4 * q], o[4 * q + 1], o[4 * q + 2], o[4 * q + 3]};
      __builtin_nontemporal_store(ov, (nfloat4*)&orow[4 * q]);
    }
  }
}

extern "C" void kernel_launch(void* const* d_in, const int* in_sizes, int n_in,
                              void* d_out, int out_size, void* d_ws, size_t ws_size,
                              hipStream_t stream) {
  const float* x = (const float*)d_in[0];
  float* out = (float*)d_out;
  dim3 grid(WW / TW, HH / TH, 8);
  dim3 block(256);
  hipLaunchKernelGGL(box_filter_v4, grid, block, 0, stream, x, out);
}

// Round 5
// 253.301 us; speedup vs baseline: 1.1271x; 1.1271x over previous
//
#include <hip/hip_runtime.h>

// BoxFilter: 21x21 all-ones box, circular pad, x: f32[8,1,2048,2048].
// v5: MLP-first. v4's VGPR_Count=52 proved the compiler serialized the 36
// phase-1 loads into dependent batches (144 VGPRs of declared live state vs
// a 52-reg budget) -> latency-bound. __launch_bounds__(256,2) lifts the VGPR
// cap to 256 so all 36 float4 loads stay in flight per thread.
// Tile 128x64 (halo redundancy 1.31x), LDS 39.9 KB. Regular float4 stores
// (v4's nt stores broke L2 write-combining: WRITE_SIZE 131->234 MB).

#define HH 2048
#define WW 2048
#define RAD 10
#define DIAM 21
#define TH 64
#define TW 128
#define NC4 38          // float4 colsum slots: image cols [w0-12, w0+139]
#define SSTR 156        // LDS row stride (dwords)

typedef float nfloat4 __attribute__((ext_vector_type(4)));

__global__ __launch_bounds__(256, 2) void box_filter_v5(
    const float* __restrict__ x, float* __restrict__ out) {
  __shared__ float sCS[TH * SSTR];  // 39936 B: colsum[r][a], a = image col - (w0-12)

  const int n = blockIdx.z;
  const int h0 = blockIdx.y * TH;
  const int w0 = blockIdx.x * TW;
  const float* __restrict__ xp = x + (size_t)n * (HH * WW);
  float* __restrict__ op = out + (size_t)n * (HH * WW);
  const int tid = threadIdx.x;

  // ---- Phase 1: vertical sliding sums, float4-vectorized columns.
  // 38 col-quads x 4 row-groups = 152 tasks. Each: 36 float4 row loads issued
  // back-to-back (all independent -> 36 outstanding 16B loads/thread), 21-tap
  // running sum slid over 16 output rows, b128 LDS writes.
  if (tid < NC4 * 4) {
    const int c4 = tid % NC4;            // 0..37
    const int g = tid / NC4;             // row-group 0..3
    const int gc = (w0 - 12 + 4 * c4) & (WW - 1);  // circular in W, 16B aligned
    const int rbase = h0 + 16 * g - RAD;
    nfloat4 v[36];
#pragma unroll
    for (int k = 0; k < 36; ++k)
      v[k] = *(const nfloat4*)(xp + (size_t)((rbase + k) & (HH - 1)) * WW + gc);
    nfloat4 s = v[0];
#pragma unroll
    for (int k = 1; k < DIAM; ++k) s += v[k];
    *(nfloat4*)&sCS[(16 * g) * SSTR + 4 * c4] = s;
#pragma unroll
    for (int i = 1; i < 16; ++i) {
      s += v[i + 20] - v[i - 1];
      *(nfloat4*)&sCS[(16 * g + i) * SSTR + 4 * c4] = s;
    }
  }
  __syncthreads();

  // ---- Phase 2: horizontal sliding sums. 64 rows x 8 chunks = 512 tasks,
  // 2 per thread. Window of 40 colsums as 10 aligned b128; output col j
  // (in chunk) sums window[j+2 .. j+22].
#pragma unroll
  for (int ii = 0; ii < 2; ++ii) {
    const int task = tid + 256 * ii;
    const int r = task >> 3;             // 0..63
    const int cg = task & 7;             // 0..7
    const float* row = &sCS[r * SSTR + 16 * cg];
    float* orow = &op[(size_t)(h0 + r) * WW + w0 + 16 * cg];
    __align__(16) float w[40];
#pragma unroll
    for (int k = 0; k < 10; ++k)
      *(nfloat4*)&w[4 * k] = *(const nfloat4*)&row[4 * k];
    float s = w[2];
#pragma unroll
    for (int k = 3; k <= 22; ++k) s += w[k];
    float o[16];
    o[0] = s;
#pragma unroll
    for (int j = 1; j < 16; ++j) {
      s += w[j + 22] - w[j + 1];
      o[j] = s;
    }
#pragma unroll
    for (int q = 0; q < 4; ++q) {
      nfloat4 ov = {o[4 * q], o[4 * q + 1], o[4 * q + 2], o[4 * q + 3]};
      *(nfloat4*)&orow[4 * q] = ov;
    }
  }
}

extern "C" void kernel_launch(void* const* d_in, const int* in_sizes, int n_in,
                              void* d_out, int out_size, void* d_ws, size_t ws_size,
                              hipStream_t stream) {
  const float* x = (const float*)d_in[0];
  float* out = (float*)d_out;
  dim3 grid(WW / TW, HH / TH, 8);
  dim3 block(256);
  hipLaunchKernelGGL(box_filter_v5, grid, block, 0, stream, x, out);
}